// Round 7
// baseline (520.785 us; speedup 1.0000x reference)
//
#include <hip/hip_runtime.h>
#include <math.h>

// Problem constants
constexpr int ROWS  = 19456;   // B*C*N = 16*19*64
constexpr int IN_DIM = 200;
constexpr int FREQ  = 101;     // rfft bins
constexpr int VQD   = 64;
constexpr int NEMB  = 8192;

typedef __attribute__((ext_vector_type(8))) short short8;   // 8 bf16 = 4 VGPRs
typedef __attribute__((ext_vector_type(4))) float floatx4;

__device__ __forceinline__ unsigned short f2bf(float v) {   // RTN-even fp32->bf16
    unsigned int u = __builtin_bit_cast(unsigned int, v);
    unsigned int r = u + 0x7fffu + ((u >> 16) & 1u);
    return (unsigned short)(r >> 16);
}
__device__ __forceinline__ float bf2f(unsigned short b) {
    unsigned int u = ((unsigned int)b) << 16;
    return __builtin_bit_cast(float, u);
}

// ---------------- workspace layout ----------------
constexpr size_t align256(size_t x) { return (x + 255) & ~(size_t)255; }
constexpr size_t SZ_FB    = (size_t)2 * ROWS * VQD * sizeof(unsigned short); // bf16 feats [2][ROWS][64]
constexpr size_t OFF_FTH  = 0;
constexpr size_t OFF_FTL  = align256(OFF_FTH + SZ_FB);
constexpr size_t SZ_CBB   = (size_t)2 * NEMB * VQD * sizeof(unsigned short); // bf16 codes [2][8192][64]
constexpr size_t OFF_CBH  = align256(OFF_FTL + SZ_FB);
constexpr size_t OFF_CBL  = align256(OFF_CBH + SZ_CBB);
constexpr size_t SZ_FD    = (size_t)2 * ROWS * VQD * sizeof(double);         // f64 feats
constexpr size_t OFF_FD   = align256(OFF_CBL + SZ_CBB);
constexpr size_t SZ_INV   = (size_t)2 * NEMB * sizeof(double);               // f64 1/||cb||
constexpr size_t OFF_INV  = align256(OFF_FD + SZ_FD);
constexpr size_t SZ_PI    = (size_t)2 * 8 * ROWS * sizeof(int);              // top-2 per 1024-chunk
constexpr size_t OFF_PI1  = align256(OFF_INV + SZ_INV);
constexpr size_t OFF_PI2  = align256(OFF_PI1 + SZ_PI);

// ---------------- 1. DFT + amp/phase + projection (f64), 8 rows per block ----------------
__global__ __launch_bounds__(128, 4) void dft_proj_kernel(
    const float* __restrict__ x, const float* __restrict__ projA, const float* __restrict__ projP,
    unsigned short* __restrict__ ftH, unsigned short* __restrict__ ftL, double* __restrict__ featD)
{
    __shared__ __align__(16) float  xsT[IN_DIM * 8];      // [n][r]  6.4 KB
    __shared__ double ampL[8 * FREQ];                     // [r][k]  6.5 KB
    __shared__ double phL [8 * FREQ];                     //         6.5 KB
    const int tid = threadIdx.x;
    const int r0 = blockIdx.x * 8;

    for (int e = tid; e < 8 * IN_DIM; e += 128) {
        int r = e / IN_DIM, n = e - r * IN_DIM;
        xsT[n * 8 + r] = x[(size_t)(r0 + r) * IN_DIM + n];
    }
    __syncthreads();

    const int k = tid;
    if (k < FREQ) {
        double c1, s1;
        if (k == 0)        { c1 =  1.0; s1 =  0.0; }
        else if (k == 50)  { c1 =  0.0; s1 = -1.0; }
        else if (k == 100) { c1 = -1.0; s1 =  0.0; }
        else {
            double ang = -6.283185307179586476925286766559 * (double)k / (double)IN_DIM;
            c1 = cos(ang); s1 = sin(ang);
        }
        double wc = 1.0, ws = 0.0;
        double re[8], im[8];
#pragma unroll
        for (int r = 0; r < 8; ++r) { re[r] = 0.0; im[r] = 0.0; }

        for (int n = 0; n < IN_DIM; ++n) {
            const float4* xp = (const float4*)(xsT + n * 8);
            float4 x0 = xp[0], x1 = xp[1];
            float xv[8] = {x0.x, x0.y, x0.z, x0.w, x1.x, x1.y, x1.z, x1.w};
#pragma unroll
            for (int r = 0; r < 8; ++r) {
                double xd = (double)xv[r];
                re[r] = fma(xd, wc, re[r]);
                im[r] = fma(xd, ws, im[r]);
            }
            double nwc = wc * c1 - ws * s1;
            double nws = wc * s1 + ws * c1;
            wc = nwc; ws = nws;
        }
#pragma unroll
        for (int r = 0; r < 8; ++r) {
            ampL[r * FREQ + k] = sqrt(re[r] * re[r] + im[r] * im[r]);
            phL [r * FREQ + k] = atan2(im[r], re[r]);
        }
    }
    __syncthreads();

    const int d = tid & 63, which = tid >> 6;
    const float*  proj = which ? projP : projA;
    const double* src  = which ? phL : ampL;
    double acc[8];
#pragma unroll
    for (int r = 0; r < 8; ++r) acc[r] = 0.0;
    for (int kk = 0; kk < FREQ; ++kk) {
        double p = (double)proj[kk * VQD + d];
#pragma unroll
        for (int r = 0; r < 8; ++r) acc[r] += src[r * FREQ + kk] * p;
    }
#pragma unroll
    for (int r = 0; r < 8; ++r) {
        size_t rowi = (size_t)which * ROWS + r0 + r;
        float vf = (float)acc[r];
        unsigned short hb = f2bf(vf);
        unsigned short lb = f2bf(vf - bf2f(hb));
        ftH[rowi * VQD + d] = hb;
        ftL[rowi * VQD + d] = lb;
        featD[rowi * VQD + d] = acc[r];
    }
}

// ---------------- 2. codebook: fold 1/||cb|| + bf16 hi/lo split + f64 inv-norm ----------------
__global__ __launch_bounds__(256) void cb_prep_kernel(
    const float* __restrict__ cbA, const float* __restrict__ cbP,
    unsigned short* __restrict__ cbH, unsigned short* __restrict__ cbL,
    double* __restrict__ invnD)
{
    __shared__ float tile[64 * 65];
    __shared__ float inv[64];
    const int tid = threadIdx.x;
    const int which = blockIdx.y;
    const int m0 = blockIdx.x * 64;
    const float* cb = which ? cbP : cbA;
    for (int e = tid; e < 4096; e += 256) {
        int c = e >> 6, d = e & 63;
        tile[c * 65 + d] = cb[(size_t)(m0 + c) * VQD + d];
    }
    __syncthreads();
    if (tid < 64) {
        double s = 0.0;
        for (int d2 = 0; d2 < 64; ++d2) { double v = (double)tile[tid * 65 + d2]; s += v * v; }
        inv[tid] = (float)(1.0 / sqrt(s));
        invnD[(size_t)which * NEMB + m0 + tid] = 1.0 / sqrt(s);
    }
    __syncthreads();
    for (int e = tid; e < 4096; e += 256) {
        int c = e >> 6, d = e & 63;
        float v = tile[c * 65 + d] * inv[c];
        unsigned short hb = f2bf(v);
        unsigned short lb = f2bf(v - bf2f(hb));
        size_t o = ((size_t)which * NEMB + m0 + c) * VQD + d;
        cbH[o] = hb; cbL[o] = lb;
    }
}

// ---------------- 3. bf16x3 MFMA sim + per-tile top-2, 64 rows/wave, staged prefetch ----------------
// grid (76, 2, 8): 256 rows x 1024 codes per block; 4 waves x 64 rows (4 groups of 16).
// Staging is register-double-buffered: tile it lives in 8 floatx4 regs, is written to LDS
// after the barrier, then tile it+1's global loads issue BEFORE the compute phase so their
// ~600-cyc latency hides under the ~2500-cyc MFMA+select phase (the round-6 profile showed
// pipes only ~55% busy -> barrier drain on staging loads was the gap).
// UPD: b2v via v_med3 (provably identical value+tie semantics to the validated round-3 form).
#define MFMA(a, b, c) __builtin_amdgcn_mfma_f32_16x16x32_bf16(a, b, c, 0, 0, 0)
#define UPD(val, s) do { float _v = (val); \
    bool _c1 = _v > b1v[s]; bool _c2 = _v > b2v[s]; \
    b2v[s] = __builtin_fmedf(_v, b1v[s], b2v[s]); \
    b2i[s] = _c1 ? b1i[s] : (_c2 ? idx : b2i[s]); \
    b1v[s] = fmaxf(b1v[s], _v); \
    b1i[s] = _c1 ? idx : b1i[s]; } while (0)

__device__ __forceinline__ float __builtin_fmedf(float a, float b, float c) {
    // median of three == new second-best given b >= c
    return fminf(fmaxf(a, c), fmaxf(fminf(a, c), b)) ; // folds to v_med3_f32
}

__global__ __launch_bounds__(256, 2) void argmax_kernel(
    const unsigned short* __restrict__ ftH, const unsigned short* __restrict__ ftL,
    const unsigned short* __restrict__ cbH, const unsigned short* __restrict__ cbL,
    int* __restrict__ pi1, int* __restrict__ pi2)
{
    __shared__ __align__(16) char lds[2 * 128 * 144];     // 36864 B
    const int tid = threadIdx.x;
    const int f = blockIdx.y, z = blockIdx.z;             // z: 1024-code chunk
    const int r0 = blockIdx.x * 256;
    const int w = tid >> 6, lane = tid & 63;
    const int q = lane >> 4, cl = lane & 15;

    const unsigned short* ftHb = ftH + (size_t)f * ROWS * VQD;
    const unsigned short* ftLb = ftL + (size_t)f * ROWS * VQD;
    const unsigned short* cbHb = cbH + (size_t)f * NEMB * VQD;
    const unsigned short* cbLb = cbL + (size_t)f * NEMB * VQD;

    // A fragments: 4 groups of 16 rows; row = r0 + w*64 + g*16 + cl; k = kb*32 + q*8 ..+8
    short8 aH[4][2], aL[4][2];
#pragma unroll
    for (int g = 0; g < 4; ++g) {
        const size_t base = (size_t)(r0 + w * 64 + g * 16 + cl) * VQD + q * 8;
        aH[g][0] = *(const short8*)(ftHb + base);
        aH[g][1] = *(const short8*)(ftHb + base + 32);
        aL[g][0] = *(const short8*)(ftLb + base);
        aL[g][1] = *(const short8*)(ftLb + base + 32);
    }

    float b1v[16], b2v[16]; int b1i[16], b2i[16];
#pragma unroll
    for (int s = 0; s < 16; ++s) { b1v[s] = -INFINITY; b2v[s] = -INFINITY; b1i[s] = 0; b2i[s] = 0; }

    const int cstage = tid >> 1, hstage = tid & 1;
    const unsigned short* sHbase = cbHb + (size_t)(z * 1024 + cstage) * VQD + hstage * 32;
    const unsigned short* sLbase = cbLb + (size_t)(z * 1024 + cstage) * VQD + hstage * 32;
    char* dH = lds + cstage * 144 + hstage * 64;
    char* dL = dH + 128 * 144;

    floatx4 sh0, sh1, sh2, sh3, sl0, sl1, sl2, sl3;
#define LOADT(t) do { \
    const floatx4* _pH = (const floatx4*)(sHbase + (size_t)(t) * 128 * VQD); \
    const floatx4* _pL = (const floatx4*)(sLbase + (size_t)(t) * 128 * VQD); \
    sh0 = _pH[0]; sh1 = _pH[1]; sh2 = _pH[2]; sh3 = _pH[3]; \
    sl0 = _pL[0]; sl1 = _pL[1]; sl2 = _pL[2]; sl3 = _pL[3]; } while (0)

    LOADT(0);
    const floatx4 zero4 = {0.f, 0.f, 0.f, 0.f};

    for (int it = 0; it < 8; ++it) {
        __syncthreads();
        ((floatx4*)dH)[0] = sh0; ((floatx4*)dH)[1] = sh1; ((floatx4*)dH)[2] = sh2; ((floatx4*)dH)[3] = sh3;
        ((floatx4*)dL)[0] = sl0; ((floatx4*)dL)[1] = sl1; ((floatx4*)dL)[2] = sl2; ((floatx4*)dL)[3] = sl3;
        __syncthreads();
        if (it < 7) LOADT(it + 1);     // latency hides under the compute below

        const int cbase = z * 1024 + it * 128;
#pragma unroll
        for (int nt = 0; nt < 8; ++nt) {
            const char* pB = lds + (nt * 16 + cl) * 144 + q * 16;
            short8 bH0 = *(const short8*)(pB);
            short8 bH1 = *(const short8*)(pB + 64);
            short8 bL0 = *(const short8*)(pB + 128 * 144);
            short8 bL1 = *(const short8*)(pB + 128 * 144 + 64);

            floatx4 acc[4];
#pragma unroll
            for (int g = 0; g < 4; ++g) acc[g] = MFMA(aH[g][0], bH0, zero4);
#pragma unroll
            for (int g = 0; g < 4; ++g) acc[g] = MFMA(aH[g][1], bH1, acc[g]);
#pragma unroll
            for (int g = 0; g < 4; ++g) acc[g] = MFMA(aH[g][0], bL0, acc[g]);
#pragma unroll
            for (int g = 0; g < 4; ++g) acc[g] = MFMA(aH[g][1], bL1, acc[g]);
#pragma unroll
            for (int g = 0; g < 4; ++g) acc[g] = MFMA(aL[g][0], bH0, acc[g]);
#pragma unroll
            for (int g = 0; g < 4; ++g) acc[g] = MFMA(aL[g][1], bH1, acc[g]);

            const int idx = cbase + nt * 16 + cl;
#pragma unroll
            for (int g = 0; g < 4; ++g)
#pragma unroll
                for (int i = 0; i < 4; ++i) UPD(acc[g][i], g * 4 + i);
        }
    }

    // final reduction in two 128-row phases (validated LDS-reduce pattern)
    float* redv = (float*)lds;                       // [128][33]
    int*   redi = (int*)(lds + 128 * 33 * 4);
    for (int ph = 0; ph < 2; ++ph) {
        __syncthreads();
        if ((w >> 1) == ph) {
#pragma unroll
            for (int s = 0; s < 16; ++s) {
                int g = s >> 2, i = s & 3;
                int rowl = (w & 1) * 64 + g * 16 + q * 4 + i;   // row within this 128-half
                int base = rowl * 33 + cl * 2;
                redv[base]     = b1v[s]; redi[base]     = b1i[s];
                redv[base + 1] = b2v[s]; redi[base + 1] = b2i[s];
            }
        }
        __syncthreads();
        if (tid < 128) {
            float v1 = -INFINITY, v2 = -INFINITY; int i1 = 0x7fffffff, i2 = 0x7fffffff;
            for (int e = 0; e < 32; ++e) {
                float v = redv[tid * 33 + e]; int id = redi[tid * 33 + e];
                if (v > v1 || (v == v1 && id < i1)) { v2 = v1; i2 = i1; v1 = v; i1 = id; }
                else if (v > v2 || (v == v2 && id < i2)) { v2 = v; i2 = id; }
            }
            size_t p = ((size_t)(f * 8 + z)) * ROWS + r0 + ph * 128 + tid;
            pi1[p] = i1; pi2[p] = i2;
        }
    }
}

// ---------------- 4. f64 rescore of the 16 candidates/row (pipelined, low-reg) ----------------
__global__ __launch_bounds__(256) void rescore_kernel(
    const double* __restrict__ featD, const double* __restrict__ invnD,
    const float* __restrict__ cbA, const float* __restrict__ cbP,
    const int* __restrict__ pi1, const int* __restrict__ pi2,
    int* __restrict__ out)
{
    const int tid = threadIdx.x;
    const int lane = tid & 63, wave = tid >> 6;
    const int task = blockIdx.x * 4 + wave;           // 0 .. 2*ROWS-1
    const int f = task / ROWS;
    const int row = task - f * ROWS;
    const float* cb = f ? cbP : cbA;
    const double fd = featD[((size_t)f * ROWS + row) * VQD + lane];

    auto cand_idx = [&](int c) -> int {
        int zz = c >> 1;
        size_t p = ((size_t)(f * 8 + zz)) * ROWS + row;
        return (c & 1) ? pi2[p] : pi1[p];
    };

    double bestv = -1.0e300; int besti = 0x7fffffff;
    int idx_c = cand_idx(0);
    double cv_c = (double)cb[(size_t)idx_c * VQD + lane];
    for (int c = 0; c < 16; ++c) {
        int idx_n = 0; double cv_n = 0.0;
        if (c < 15) {                                  // prefetch next candidate
            idx_n = cand_idx(c + 1);
            cv_n = (double)cb[(size_t)idx_n * VQD + lane];
        }
        double t = fd * cv_c;
        for (int m = 32; m >= 1; m >>= 1) t += __shfl_xor(t, m, 64);
        double sim = t * invnD[(size_t)f * NEMB + idx_c];
        if (sim > bestv || (sim == bestv && idx_c < besti)) { bestv = sim; besti = idx_c; }
        idx_c = idx_n; cv_c = cv_n;
    }
    if (lane == 0) out[task] = besti;
}

// ---------------- launch ----------------
extern "C" void kernel_launch(void* const* d_in, const int* in_sizes, int n_in,
                              void* d_out, int out_size, void* d_ws, size_t ws_size,
                              hipStream_t stream)
{
    const float* x     = (const float*)d_in[0];
    const float* projA = (const float*)d_in[1];
    const float* projP = (const float*)d_in[2];
    const float* cbA   = (const float*)d_in[3];
    const float* cbP   = (const float*)d_in[4];

    char* ws = (char*)d_ws;
    unsigned short* ftH   = (unsigned short*)(ws + OFF_FTH);
    unsigned short* ftL   = (unsigned short*)(ws + OFF_FTL);
    unsigned short* cbHp  = (unsigned short*)(ws + OFF_CBH);
    unsigned short* cbLp  = (unsigned short*)(ws + OFF_CBL);
    double*         featD = (double*)(ws + OFF_FD);
    double*         invnD = (double*)(ws + OFF_INV);
    int*            pi1   = (int*)(ws + OFF_PI1);
    int*            pi2   = (int*)(ws + OFF_PI2);

    dft_proj_kernel<<<ROWS / 8, 128, 0, stream>>>(x, projA, projP, ftH, ftL, featD);
    cb_prep_kernel<<<dim3(NEMB / 64, 2), 256, 0, stream>>>(cbA, cbP, cbHp, cbLp, invnD);
    argmax_kernel<<<dim3(ROWS / 256, 2, 8), 256, 0, stream>>>(ftH, ftL, cbHp, cbLp, pi1, pi2);
    rescore_kernel<<<(2 * ROWS) / 4, 256, 0, stream>>>(featD, invnD, cbA, cbP, pi1, pi2, (int*)d_out);
}

// Round 8
// 347.507 us; speedup vs baseline: 1.4986x; 1.4986x over previous
//
#include <hip/hip_runtime.h>
#include <math.h>

// Problem constants
constexpr int ROWS  = 19456;   // B*C*N = 16*19*64
constexpr int IN_DIM = 200;
constexpr int FREQ  = 101;     // rfft bins
constexpr int VQD   = 64;
constexpr int NEMB  = 8192;

typedef __attribute__((ext_vector_type(8))) short short8;   // 8 bf16 = 4 VGPRs
typedef __attribute__((ext_vector_type(4))) float floatx4;

__device__ __forceinline__ unsigned short f2bf(float v) {   // RTN-even fp32->bf16
    unsigned int u = __builtin_bit_cast(unsigned int, v);
    unsigned int r = u + 0x7fffu + ((u >> 16) & 1u);
    return (unsigned short)(r >> 16);
}
__device__ __forceinline__ float bf2f(unsigned short b) {
    unsigned int u = ((unsigned int)b) << 16;
    return __builtin_bit_cast(float, u);
}

// ---------------- workspace layout ----------------
constexpr size_t align256(size_t x) { return (x + 255) & ~(size_t)255; }
constexpr size_t SZ_FB    = (size_t)2 * ROWS * VQD * sizeof(unsigned short); // bf16 feats [2][ROWS][64]
constexpr size_t OFF_FTH  = 0;
constexpr size_t OFF_FTL  = align256(OFF_FTH + SZ_FB);
constexpr size_t SZ_CBB   = (size_t)2 * NEMB * VQD * sizeof(unsigned short); // bf16 codes [2][8192][64]
constexpr size_t OFF_CBH  = align256(OFF_FTL + SZ_FB);
constexpr size_t OFF_CBL  = align256(OFF_CBH + SZ_CBB);
constexpr size_t SZ_FD    = (size_t)2 * ROWS * VQD * sizeof(double);         // f64 feats
constexpr size_t OFF_FD   = align256(OFF_CBL + SZ_CBB);
constexpr size_t SZ_INV   = (size_t)2 * NEMB * sizeof(double);               // f64 1/||cb||
constexpr size_t OFF_INV  = align256(OFF_FD + SZ_FD);
constexpr size_t SZ_PI    = (size_t)2 * 4 * ROWS * sizeof(int);              // top-2 per 2048-chunk
constexpr size_t OFF_PI1  = align256(OFF_INV + SZ_INV);
constexpr size_t OFF_PI2  = align256(OFF_PI1 + SZ_PI);

// ---------------- 1. DFT + amp/phase + projection (f64), 8 rows per block ----------------
// (validated rounds 5-7; fused twiddle via per-lane complex rotation recurrence)
__global__ __launch_bounds__(128, 4) void dft_proj_kernel(
    const float* __restrict__ x, const float* __restrict__ projA, const float* __restrict__ projP,
    unsigned short* __restrict__ ftH, unsigned short* __restrict__ ftL, double* __restrict__ featD)
{
    __shared__ __align__(16) float  xsT[IN_DIM * 8];      // [n][r]  6.4 KB
    __shared__ double ampL[8 * FREQ];                     // [r][k]  6.5 KB
    __shared__ double phL [8 * FREQ];                     //         6.5 KB
    const int tid = threadIdx.x;
    const int r0 = blockIdx.x * 8;

    for (int e = tid; e < 8 * IN_DIM; e += 128) {
        int r = e / IN_DIM, n = e - r * IN_DIM;
        xsT[n * 8 + r] = x[(size_t)(r0 + r) * IN_DIM + n];
    }
    __syncthreads();

    const int k = tid;
    if (k < FREQ) {
        double c1, s1;
        if (k == 0)        { c1 =  1.0; s1 =  0.0; }
        else if (k == 50)  { c1 =  0.0; s1 = -1.0; }
        else if (k == 100) { c1 = -1.0; s1 =  0.0; }
        else {
            double ang = -6.283185307179586476925286766559 * (double)k / (double)IN_DIM;
            c1 = cos(ang); s1 = sin(ang);
        }
        double wc = 1.0, ws = 0.0;
        double re[8], im[8];
#pragma unroll
        for (int r = 0; r < 8; ++r) { re[r] = 0.0; im[r] = 0.0; }

        for (int n = 0; n < IN_DIM; ++n) {
            const float4* xp = (const float4*)(xsT + n * 8);
            float4 x0 = xp[0], x1 = xp[1];
            float xv[8] = {x0.x, x0.y, x0.z, x0.w, x1.x, x1.y, x1.z, x1.w};
#pragma unroll
            for (int r = 0; r < 8; ++r) {
                double xd = (double)xv[r];
                re[r] = fma(xd, wc, re[r]);
                im[r] = fma(xd, ws, im[r]);
            }
            double nwc = wc * c1 - ws * s1;
            double nws = wc * s1 + ws * c1;
            wc = nwc; ws = nws;
        }
#pragma unroll
        for (int r = 0; r < 8; ++r) {
            ampL[r * FREQ + k] = sqrt(re[r] * re[r] + im[r] * im[r]);
            phL [r * FREQ + k] = atan2(im[r], re[r]);
        }
    }
    __syncthreads();

    const int d = tid & 63, which = tid >> 6;
    const float*  proj = which ? projP : projA;
    const double* src  = which ? phL : ampL;
    double acc[8];
#pragma unroll
    for (int r = 0; r < 8; ++r) acc[r] = 0.0;
    for (int kk = 0; kk < FREQ; ++kk) {
        double p = (double)proj[kk * VQD + d];
#pragma unroll
        for (int r = 0; r < 8; ++r) acc[r] += src[r * FREQ + kk] * p;
    }
#pragma unroll
    for (int r = 0; r < 8; ++r) {
        size_t rowi = (size_t)which * ROWS + r0 + r;
        float vf = (float)acc[r];
        unsigned short hb = f2bf(vf);
        unsigned short lb = f2bf(vf - bf2f(hb));
        ftH[rowi * VQD + d] = hb;
        ftL[rowi * VQD + d] = lb;
        featD[rowi * VQD + d] = acc[r];
    }
}

// ---------------- 2. codebook: fold 1/||cb|| + bf16 hi/lo split + f64 inv-norm ----------------
__global__ __launch_bounds__(256) void cb_prep_kernel(
    const float* __restrict__ cbA, const float* __restrict__ cbP,
    unsigned short* __restrict__ cbH, unsigned short* __restrict__ cbL,
    double* __restrict__ invnD)
{
    __shared__ float tile[64 * 65];
    __shared__ float inv[64];
    const int tid = threadIdx.x;
    const int which = blockIdx.y;
    const int m0 = blockIdx.x * 64;
    const float* cb = which ? cbP : cbA;
    for (int e = tid; e < 4096; e += 256) {
        int c = e >> 6, d = e & 63;
        tile[c * 65 + d] = cb[(size_t)(m0 + c) * VQD + d];
    }
    __syncthreads();
    if (tid < 64) {
        double s = 0.0;
        for (int d2 = 0; d2 < 64; ++d2) { double v = (double)tile[tid * 65 + d2]; s += v * v; }
        inv[tid] = (float)(1.0 / sqrt(s));
        invnD[(size_t)which * NEMB + m0 + tid] = 1.0 / sqrt(s);
    }
    __syncthreads();
    for (int e = tid; e < 4096; e += 256) {
        int c = e >> 6, d = e & 63;
        float v = tile[c * 65 + d] * inv[c];
        unsigned short hb = f2bf(v);
        unsigned short lb = f2bf(v - bf2f(hb));
        size_t o = ((size_t)which * NEMB + m0 + c) * VQD + d;
        cbH[o] = hb; cbL[o] = lb;
    }
}

// ---------------- 3. bf16x3 MFMA sim + per-tile top-2 (exact round-3 structure, 156 us) ----------------
// grid (152, 2, 4): 128 rows x 2048 codes per block; 4 waves, each wave 32 rows.
// Four structural variants (pool4 r4, pool2 r5, 64-rows r6, reg-dbuf r7) all regressed;
// this is the best measured configuration. Do not "improve" without new counter evidence.
#define MFMA(a, b, c) __builtin_amdgcn_mfma_f32_16x16x32_bf16(a, b, c, 0, 0, 0)
#define UPD(val, s) do { float _v = (val); \
    bool _c1 = _v > b1v[s]; bool _c2 = _v > b2v[s]; \
    b2v[s] = _c1 ? b1v[s] : (_c2 ? _v : b2v[s]); \
    b2i[s] = _c1 ? b1i[s] : (_c2 ? idx : b2i[s]); \
    b1v[s] = _c1 ? _v : b1v[s]; \
    b1i[s] = _c1 ? idx : b1i[s]; } while (0)

__global__ __launch_bounds__(256, 3) void argmax_kernel(
    const unsigned short* __restrict__ ftH, const unsigned short* __restrict__ ftL,
    const unsigned short* __restrict__ cbH, const unsigned short* __restrict__ cbL,
    int* __restrict__ pi1, int* __restrict__ pi2)
{
    __shared__ __align__(16) char lds[2 * 128 * 144];     // 36864 B
    const int tid = threadIdx.x;
    const int f = blockIdx.y, z = blockIdx.z;
    const int r0 = blockIdx.x * 128;
    const int w = tid >> 6, lane = tid & 63;
    const int q = lane >> 4, cl = lane & 15;

    const unsigned short* ftHb = ftH + (size_t)f * ROWS * VQD;
    const unsigned short* ftLb = ftL + (size_t)f * ROWS * VQD;
    const unsigned short* cbHb = cbH + (size_t)f * NEMB * VQD;
    const unsigned short* cbLb = cbL + (size_t)f * NEMB * VQD;

    // A fragments: rows r0 + w*32 + {cl, 16+cl}; per-lane k = kb*32 + q*8 .. +8
    short8 aH00, aH01, aH10, aH11, aL00, aL01, aL10, aL11;
    {
        const size_t baseA = (size_t)(r0 + w * 32 + cl) * VQD + q * 8;
        const size_t baseB = baseA + (size_t)16 * VQD;
        aH00 = *(const short8*)(ftHb + baseA);
        aH01 = *(const short8*)(ftHb + baseA + 32);
        aH10 = *(const short8*)(ftHb + baseB);
        aH11 = *(const short8*)(ftHb + baseB + 32);
        aL00 = *(const short8*)(ftLb + baseA);
        aL01 = *(const short8*)(ftLb + baseA + 32);
        aL10 = *(const short8*)(ftLb + baseB);
        aL11 = *(const short8*)(ftLb + baseB + 32);
    }

    float b1v[8], b2v[8]; int b1i[8], b2i[8];
#pragma unroll
    for (int s = 0; s < 8; ++s) { b1v[s] = -INFINITY; b2v[s] = -INFINITY; b1i[s] = 0; b2i[s] = 0; }

    const int cstage = tid >> 1, hstage = tid & 1;
    const size_t gsoff = (size_t)(z * 2048) * VQD;

    for (int it = 0; it < 16; ++it) {
        __syncthreads();
        {   // stage 128 codes (hi+lo): thread -> (code=tid>>1, 32-elem half=tid&1)
            const unsigned short* sH = cbHb + gsoff + (size_t)(it * 128 + cstage) * VQD + hstage * 32;
            const unsigned short* sL = cbLb + gsoff + (size_t)(it * 128 + cstage) * VQD + hstage * 32;
            char* dH = lds + cstage * 144 + hstage * 64;
            char* dL = dH + 128 * 144;
            floatx4 h0 = ((const floatx4*)sH)[0], h1 = ((const floatx4*)sH)[1];
            floatx4 h2 = ((const floatx4*)sH)[2], h3 = ((const floatx4*)sH)[3];
            floatx4 l0 = ((const floatx4*)sL)[0], l1 = ((const floatx4*)sL)[1];
            floatx4 l2 = ((const floatx4*)sL)[2], l3 = ((const floatx4*)sL)[3];
            ((floatx4*)dH)[0] = h0; ((floatx4*)dH)[1] = h1; ((floatx4*)dH)[2] = h2; ((floatx4*)dH)[3] = h3;
            ((floatx4*)dL)[0] = l0; ((floatx4*)dL)[1] = l1; ((floatx4*)dL)[2] = l2; ((floatx4*)dL)[3] = l3;
        }
        __syncthreads();

        const int cbase = z * 2048 + it * 128;
#pragma unroll
        for (int nt = 0; nt < 8; ++nt) {
            const char* pB = lds + (nt * 16 + cl) * 144 + q * 16;
            short8 bH0 = *(const short8*)(pB);
            short8 bH1 = *(const short8*)(pB + 64);
            short8 bL0 = *(const short8*)(pB + 128 * 144);
            short8 bL1 = *(const short8*)(pB + 128 * 144 + 64);

            floatx4 acc0 = {0.f, 0.f, 0.f, 0.f};
            floatx4 acc1 = {0.f, 0.f, 0.f, 0.f};
            acc0 = MFMA(aH00, bH0, acc0);  acc1 = MFMA(aH10, bH0, acc1);
            acc0 = MFMA(aH01, bH1, acc0);  acc1 = MFMA(aH11, bH1, acc1);
            acc0 = MFMA(aH00, bL0, acc0);  acc1 = MFMA(aH10, bL0, acc1);
            acc0 = MFMA(aH01, bL1, acc0);  acc1 = MFMA(aH11, bL1, acc1);
            acc0 = MFMA(aL00, bH0, acc0);  acc1 = MFMA(aL10, bH0, acc1);
            acc0 = MFMA(aL01, bH1, acc0);  acc1 = MFMA(aL11, bH1, acc1);

            const int idx = cbase + nt * 16 + cl;
#pragma unroll
            for (int i = 0; i < 4; ++i) { UPD(acc0[i], i); UPD(acc1[i], 4 + i); }
        }
    }

    // block reduction: per-lane top-2 (col-slice cl) -> per-row top-2 of 2048
    __syncthreads();
    float* redv = (float*)lds;           // [128][33]
    int*   redi = (int*)(lds + 128 * 33 * 4);
#pragma unroll
    for (int s = 0; s < 8; ++s) {
        int rowl = w * 32 + ((s & 4) << 2) + q * 4 + (s & 3);   // +16 when s>=4
        int base = rowl * 33 + cl * 2;
        redv[base]     = b1v[s]; redi[base]     = b1i[s];
        redv[base + 1] = b2v[s]; redi[base + 1] = b2i[s];
    }
    __syncthreads();
    if (tid < 128) {
        float v1 = -INFINITY, v2 = -INFINITY; int i1 = 0x7fffffff, i2 = 0x7fffffff;
        for (int e = 0; e < 32; ++e) {
            float v = redv[tid * 33 + e]; int id = redi[tid * 33 + e];
            if (v > v1 || (v == v1 && id < i1)) { v2 = v1; i2 = i1; v1 = v; i1 = id; }
            else if (v > v2 || (v == v2 && id < i2)) { v2 = v; i2 = id; }
        }
        size_t p = ((size_t)(f * 4 + z)) * ROWS + r0 + tid;
        pi1[p] = i1; pi2[p] = i2;
    }
}

// ---------------- 4. f64 rescore of the 8 candidates/row (round-5 version) ----------------
__global__ __launch_bounds__(256) void rescore_kernel(
    const double* __restrict__ featD, const double* __restrict__ invnD,
    const float* __restrict__ cbA, const float* __restrict__ cbP,
    const int* __restrict__ pi1, const int* __restrict__ pi2,
    int* __restrict__ out)
{
    const int tid = threadIdx.x;
    const int lane = tid & 63, wave = tid >> 6;
    const int task = blockIdx.x * 4 + wave;           // 0 .. 2*ROWS-1
    const int f = task / ROWS;
    const int row = task - f * ROWS;
    const float* cb = f ? cbP : cbA;
    const double fd = featD[((size_t)f * ROWS + row) * VQD + lane];

    int idxs[8];
#pragma unroll
    for (int c = 0; c < 8; ++c) {
        int zz = c >> 1;
        size_t p = ((size_t)(f * 4 + zz)) * ROWS + row;
        idxs[c] = (c & 1) ? pi2[p] : pi1[p];
    }
    double cv[8];
#pragma unroll
    for (int c = 0; c < 8; ++c)
        cv[c] = (double)cb[(size_t)idxs[c] * VQD + lane];

    double bestv = -1.0e300; int besti = 0x7fffffff;
#pragma unroll
    for (int c = 0; c < 8; ++c) {
        double t = fd * cv[c];
        for (int m = 32; m >= 1; m >>= 1) t += __shfl_xor(t, m, 64);
        double sim = t * invnD[(size_t)f * NEMB + idxs[c]];
        int idx = idxs[c];
        if (sim > bestv || (sim == bestv && idx < besti)) { bestv = sim; besti = idx; }
    }
    if (lane == 0) out[task] = besti;
}

// ---------------- launch ----------------
extern "C" void kernel_launch(void* const* d_in, const int* in_sizes, int n_in,
                              void* d_out, int out_size, void* d_ws, size_t ws_size,
                              hipStream_t stream)
{
    const float* x     = (const float*)d_in[0];
    const float* projA = (const float*)d_in[1];
    const float* projP = (const float*)d_in[2];
    const float* cbA   = (const float*)d_in[3];
    const float* cbP   = (const float*)d_in[4];

    char* ws = (char*)d_ws;
    unsigned short* ftH   = (unsigned short*)(ws + OFF_FTH);
    unsigned short* ftL   = (unsigned short*)(ws + OFF_FTL);
    unsigned short* cbHp  = (unsigned short*)(ws + OFF_CBH);
    unsigned short* cbLp  = (unsigned short*)(ws + OFF_CBL);
    double*         featD = (double*)(ws + OFF_FD);
    double*         invnD = (double*)(ws + OFF_INV);
    int*            pi1   = (int*)(ws + OFF_PI1);
    int*            pi2   = (int*)(ws + OFF_PI2);

    dft_proj_kernel<<<ROWS / 8, 128, 0, stream>>>(x, projA, projP, ftH, ftL, featD);
    cb_prep_kernel<<<dim3(NEMB / 64, 2), 256, 0, stream>>>(cbA, cbP, cbHp, cbLp, invnD);
    argmax_kernel<<<dim3(ROWS / 128, 2, 4), 256, 0, stream>>>(ftH, ftL, cbHp, cbLp, pi1, pi2);
    rescore_kernel<<<(2 * ROWS) / 4, 256, 0, stream>>>(featD, invnD, cbA, cbP, pi1, pi2, (int*)d_out);
}

// Round 9
// 345.937 us; speedup vs baseline: 1.5054x; 1.0045x over previous
//
#include <hip/hip_runtime.h>
#include <math.h>

// Problem constants
constexpr int ROWS  = 19456;   // B*C*N = 16*19*64
constexpr int IN_DIM = 200;
constexpr int FREQ  = 101;     // rfft bins
constexpr int VQD   = 64;
constexpr int NEMB  = 8192;

typedef __attribute__((ext_vector_type(8))) short short8;   // 8 bf16 = 4 VGPRs
typedef __attribute__((ext_vector_type(4))) float floatx4;

__device__ __forceinline__ unsigned short f2bf(float v) {   // RTN-even fp32->bf16
    unsigned int u = __builtin_bit_cast(unsigned int, v);
    unsigned int r = u + 0x7fffu + ((u >> 16) & 1u);
    return (unsigned short)(r >> 16);
}
__device__ __forceinline__ float bf2f(unsigned short b) {
    unsigned int u = ((unsigned int)b) << 16;
    return __builtin_bit_cast(float, u);
}

// async global->LDS DMA, 16 B per lane; LDS dest = wave-uniform base + lane*16
#define GLOAD_LDS(gp, lp) __builtin_amdgcn_global_load_lds( \
    (const __attribute__((address_space(1))) unsigned int*)(gp), \
    (__attribute__((address_space(3))) unsigned int*)(lp), 16, 0, 0)

// ---------------- workspace layout ----------------
constexpr size_t align256(size_t x) { return (x + 255) & ~(size_t)255; }
constexpr size_t SZ_FB    = (size_t)2 * ROWS * VQD * sizeof(unsigned short); // bf16 feats [2][ROWS][64]
constexpr size_t OFF_FTH  = 0;
constexpr size_t OFF_FTL  = align256(OFF_FTH + SZ_FB);
constexpr size_t SZ_CBB   = (size_t)2 * NEMB * VQD * sizeof(unsigned short); // bf16 codes [2][8192][64]
constexpr size_t OFF_CBH  = align256(OFF_FTL + SZ_FB);
constexpr size_t OFF_CBL  = align256(OFF_CBH + SZ_CBB);
constexpr size_t SZ_FD    = (size_t)2 * ROWS * VQD * sizeof(double);         // f64 feats
constexpr size_t OFF_FD   = align256(OFF_CBL + SZ_CBB);
constexpr size_t SZ_INV   = (size_t)2 * NEMB * sizeof(double);               // f64 1/||cb||
constexpr size_t OFF_INV  = align256(OFF_FD + SZ_FD);
constexpr size_t SZ_PI    = (size_t)2 * 4 * ROWS * sizeof(int);              // top-2 per 2048-chunk
constexpr size_t OFF_PI1  = align256(OFF_INV + SZ_INV);
constexpr size_t OFF_PI2  = align256(OFF_PI1 + SZ_PI);

// ---------------- 1. DFT + amp/phase + projection (f64), 8 rows per block ----------------
// (validated rounds 5-8; fused twiddle via per-lane complex rotation recurrence)
__global__ __launch_bounds__(128, 4) void dft_proj_kernel(
    const float* __restrict__ x, const float* __restrict__ projA, const float* __restrict__ projP,
    unsigned short* __restrict__ ftH, unsigned short* __restrict__ ftL, double* __restrict__ featD)
{
    __shared__ __align__(16) float  xsT[IN_DIM * 8];      // [n][r]  6.4 KB
    __shared__ double ampL[8 * FREQ];                     // [r][k]  6.5 KB
    __shared__ double phL [8 * FREQ];                     //         6.5 KB
    const int tid = threadIdx.x;
    const int r0 = blockIdx.x * 8;

    for (int e = tid; e < 8 * IN_DIM; e += 128) {
        int r = e / IN_DIM, n = e - r * IN_DIM;
        xsT[n * 8 + r] = x[(size_t)(r0 + r) * IN_DIM + n];
    }
    __syncthreads();

    const int k = tid;
    if (k < FREQ) {
        double c1, s1;
        if (k == 0)        { c1 =  1.0; s1 =  0.0; }
        else if (k == 50)  { c1 =  0.0; s1 = -1.0; }
        else if (k == 100) { c1 = -1.0; s1 =  0.0; }
        else {
            double ang = -6.283185307179586476925286766559 * (double)k / (double)IN_DIM;
            c1 = cos(ang); s1 = sin(ang);
        }
        double wc = 1.0, ws = 0.0;
        double re[8], im[8];
#pragma unroll
        for (int r = 0; r < 8; ++r) { re[r] = 0.0; im[r] = 0.0; }

        for (int n = 0; n < IN_DIM; ++n) {
            const float4* xp = (const float4*)(xsT + n * 8);
            float4 x0 = xp[0], x1 = xp[1];
            float xv[8] = {x0.x, x0.y, x0.z, x0.w, x1.x, x1.y, x1.z, x1.w};
#pragma unroll
            for (int r = 0; r < 8; ++r) {
                double xd = (double)xv[r];
                re[r] = fma(xd, wc, re[r]);
                im[r] = fma(xd, ws, im[r]);
            }
            double nwc = wc * c1 - ws * s1;
            double nws = wc * s1 + ws * c1;
            wc = nwc; ws = nws;
        }
#pragma unroll
        for (int r = 0; r < 8; ++r) {
            ampL[r * FREQ + k] = sqrt(re[r] * re[r] + im[r] * im[r]);
            phL [r * FREQ + k] = atan2(im[r], re[r]);
        }
    }
    __syncthreads();

    const int d = tid & 63, which = tid >> 6;
    const float*  proj = which ? projP : projA;
    const double* src  = which ? phL : ampL;
    double acc[8];
#pragma unroll
    for (int r = 0; r < 8; ++r) acc[r] = 0.0;
    for (int kk = 0; kk < FREQ; ++kk) {
        double p = (double)proj[kk * VQD + d];
#pragma unroll
        for (int r = 0; r < 8; ++r) acc[r] += src[r * FREQ + kk] * p;
    }
#pragma unroll
    for (int r = 0; r < 8; ++r) {
        size_t rowi = (size_t)which * ROWS + r0 + r;
        float vf = (float)acc[r];
        unsigned short hb = f2bf(vf);
        unsigned short lb = f2bf(vf - bf2f(hb));
        ftH[rowi * VQD + d] = hb;
        ftL[rowi * VQD + d] = lb;
        featD[rowi * VQD + d] = acc[r];
    }
}

// ---------------- 2. codebook: fold 1/||cb|| + bf16 hi/lo split + f64 inv-norm ----------------
__global__ __launch_bounds__(256) void cb_prep_kernel(
    const float* __restrict__ cbA, const float* __restrict__ cbP,
    unsigned short* __restrict__ cbH, unsigned short* __restrict__ cbL,
    double* __restrict__ invnD)
{
    __shared__ float tile[64 * 65];
    __shared__ float inv[64];
    const int tid = threadIdx.x;
    const int which = blockIdx.y;
    const int m0 = blockIdx.x * 64;
    const float* cb = which ? cbP : cbA;
    for (int e = tid; e < 4096; e += 256) {
        int c = e >> 6, d = e & 63;
        tile[c * 65 + d] = cb[(size_t)(m0 + c) * VQD + d];
    }
    __syncthreads();
    if (tid < 64) {
        double s = 0.0;
        for (int d2 = 0; d2 < 64; ++d2) { double v = (double)tile[tid * 65 + d2]; s += v * v; }
        inv[tid] = (float)(1.0 / sqrt(s));
        invnD[(size_t)which * NEMB + m0 + tid] = 1.0 / sqrt(s);
    }
    __syncthreads();
    for (int e = tid; e < 4096; e += 256) {
        int c = e >> 6, d = e & 63;
        float v = tile[c * 65 + d] * inv[c];
        unsigned short hb = f2bf(v);
        unsigned short lb = f2bf(v - bf2f(hb));
        size_t o = ((size_t)which * NEMB + m0 + c) * VQD + d;
        cbH[o] = hb; cbL[o] = lb;
    }
}

// ---------------- 3. bf16x3 MFMA sim + per-tile top-2, async DMA staging ----------------
// Round-3/8 structure (best measured) with ONE change: staging via global_load_lds
// width=16 (the m93->m97 ladder move) instead of VGPR round-trip + ds_write.
// LDS layout is XOR-swizzled, unpadded: chunk j of code c at c*128 + (j^(c&7))*16.
//  - staging: lane pattern is exactly linear-offset-compatible (32 == 0 mod 8), source
//    reads stay 128-B coalesced (chunks permuted within a code row only)
//  - B-reads: bank group 4*(q^(cl&7)) mod 32 -- same 8-lane/4-bank distribution as the
//    validated padded-144 layout, so read conflicts are unchanged
//  - fragment contents bit-identical -> scores, selection, output all bitwise unchanged
#define MFMA(a, b, c) __builtin_amdgcn_mfma_f32_16x16x32_bf16(a, b, c, 0, 0, 0)
#define UPD(val, s) do { float _v = (val); \
    bool _c1 = _v > b1v[s]; bool _c2 = _v > b2v[s]; \
    b2v[s] = _c1 ? b1v[s] : (_c2 ? _v : b2v[s]); \
    b2i[s] = _c1 ? b1i[s] : (_c2 ? idx : b2i[s]); \
    b1v[s] = _c1 ? _v : b1v[s]; \
    b1i[s] = _c1 ? idx : b1i[s]; } while (0)

__global__ __launch_bounds__(256, 3) void argmax_kernel(
    const unsigned short* __restrict__ ftH, const unsigned short* __restrict__ ftL,
    const unsigned short* __restrict__ cbH, const unsigned short* __restrict__ cbL,
    int* __restrict__ pi1, int* __restrict__ pi2)
{
    // 32768 B tiles (H 0..16K, L 16K..32K) + reduction needs 33792 B total
    __shared__ __align__(16) char lds[33792];
    const int tid = threadIdx.x;
    const int f = blockIdx.y, z = blockIdx.z;
    const int r0 = blockIdx.x * 128;
    const int w = tid >> 6, lane = tid & 63;
    const int q = lane >> 4, cl = lane & 15;

    const unsigned short* ftHb = ftH + (size_t)f * ROWS * VQD;
    const unsigned short* ftLb = ftL + (size_t)f * ROWS * VQD;
    const unsigned short* cbHb = cbH + (size_t)f * NEMB * VQD;
    const unsigned short* cbLb = cbL + (size_t)f * NEMB * VQD;

    // A fragments: rows r0 + w*32 + {cl, 16+cl}; per-lane k = kb*32 + q*8 .. +8
    short8 aH00, aH01, aH10, aH11, aL00, aL01, aL10, aL11;
    {
        const size_t baseA = (size_t)(r0 + w * 32 + cl) * VQD + q * 8;
        const size_t baseB = baseA + (size_t)16 * VQD;
        aH00 = *(const short8*)(ftHb + baseA);
        aH01 = *(const short8*)(ftHb + baseA + 32);
        aH10 = *(const short8*)(ftHb + baseB);
        aH11 = *(const short8*)(ftHb + baseB + 32);
        aL00 = *(const short8*)(ftLb + baseA);
        aL01 = *(const short8*)(ftLb + baseA + 32);
        aL10 = *(const short8*)(ftLb + baseB);
        aL11 = *(const short8*)(ftLb + baseB + 32);
    }

    float b1v[8], b2v[8]; int b1i[8], b2i[8];
#pragma unroll
    for (int s = 0; s < 8; ++s) { b1v[s] = -INFINITY; b2v[s] = -INFINITY; b1i[s] = 0; b2i[s] = 0; }

    // staging source: thread -> codeBase = tid>>3 (+32 per round), chunk j = (tid&7)^(codeBase&7)
    const int cBase = tid >> 3;
    const int jel   = (((tid & 7) ^ (cBase & 7)) << 3);     // element offset of chunk
    const unsigned short* gH = cbHb + (size_t)(z * 2048 + cBase) * VQD + jel;
    const unsigned short* gL = cbLb + (size_t)(z * 2048 + cBase) * VQD + jel;

    // swizzled B-read offsets (actual chunks q and q+4 of code nt*16+cl)
    const int p0 = ((q ^ (cl & 7)) << 4);
    const int p1 = p0 ^ 64;

    for (int it = 0; it < 16; ++it) {
        __syncthreads();
#pragma unroll
        for (int r = 0; r < 4; ++r) {       // 8 async DMA issues, no VGPR round-trip
            const size_t gofs = (size_t)(it * 128 + 32 * r) * VQD;
            GLOAD_LDS(gH + gofs, lds + w * 1024 + r * 4096);
            GLOAD_LDS(gL + gofs, lds + 16384 + w * 1024 + r * 4096);
        }
        __syncthreads();                     // compiler drains vmcnt(0) before s_barrier

        const int cbase = z * 2048 + it * 128;
#pragma unroll
        for (int nt = 0; nt < 8; ++nt) {
            const char* row = lds + (nt * 16 + cl) * 128;
            short8 bH0 = *(const short8*)(row + p0);
            short8 bH1 = *(const short8*)(row + p1);
            short8 bL0 = *(const short8*)(row + 16384 + p0);
            short8 bL1 = *(const short8*)(row + 16384 + p1);

            floatx4 acc0 = {0.f, 0.f, 0.f, 0.f};
            floatx4 acc1 = {0.f, 0.f, 0.f, 0.f};
            acc0 = MFMA(aH00, bH0, acc0);  acc1 = MFMA(aH10, bH0, acc1);
            acc0 = MFMA(aH01, bH1, acc0);  acc1 = MFMA(aH11, bH1, acc1);
            acc0 = MFMA(aH00, bL0, acc0);  acc1 = MFMA(aH10, bL0, acc1);
            acc0 = MFMA(aH01, bL1, acc0);  acc1 = MFMA(aH11, bL1, acc1);
            acc0 = MFMA(aL00, bH0, acc0);  acc1 = MFMA(aL10, bH0, acc1);
            acc0 = MFMA(aL01, bH1, acc0);  acc1 = MFMA(aL11, bH1, acc1);

            const int idx = cbase + nt * 16 + cl;
#pragma unroll
            for (int i = 0; i < 4; ++i) { UPD(acc0[i], i); UPD(acc1[i], 4 + i); }
        }
    }

    // block reduction: per-lane top-2 (col-slice cl) -> per-row top-2 of 2048
    __syncthreads();
    float* redv = (float*)lds;           // [128][33]
    int*   redi = (int*)(lds + 128 * 33 * 4);
#pragma unroll
    for (int s = 0; s < 8; ++s) {
        int rowl = w * 32 + ((s & 4) << 2) + q * 4 + (s & 3);   // +16 when s>=4
        int base = rowl * 33 + cl * 2;
        redv[base]     = b1v[s]; redi[base]     = b1i[s];
        redv[base + 1] = b2v[s]; redi[base + 1] = b2i[s];
    }
    __syncthreads();
    if (tid < 128) {
        float v1 = -INFINITY, v2 = -INFINITY; int i1 = 0x7fffffff, i2 = 0x7fffffff;
        for (int e = 0; e < 32; ++e) {
            float v = redv[tid * 33 + e]; int id = redi[tid * 33 + e];
            if (v > v1 || (v == v1 && id < i1)) { v2 = v1; i2 = i1; v1 = v; i1 = id; }
            else if (v > v2 || (v == v2 && id < i2)) { v2 = v; i2 = id; }
        }
        size_t p = ((size_t)(f * 4 + z)) * ROWS + r0 + tid;
        pi1[p] = i1; pi2[p] = i2;
    }
}

// ---------------- 4. f64 rescore of the 8 candidates/row (round-5 version) ----------------
__global__ __launch_bounds__(256) void rescore_kernel(
    const double* __restrict__ featD, const double* __restrict__ invnD,
    const float* __restrict__ cbA, const float* __restrict__ cbP,
    const int* __restrict__ pi1, const int* __restrict__ pi2,
    int* __restrict__ out)
{
    const int tid = threadIdx.x;
    const int lane = tid & 63, wave = tid >> 6;
    const int task = blockIdx.x * 4 + wave;           // 0 .. 2*ROWS-1
    const int f = task / ROWS;
    const int row = task - f * ROWS;
    const float* cb = f ? cbP : cbA;
    const double fd = featD[((size_t)f * ROWS + row) * VQD + lane];

    int idxs[8];
#pragma unroll
    for (int c = 0; c < 8; ++c) {
        int zz = c >> 1;
        size_t p = ((size_t)(f * 4 + zz)) * ROWS + row;
        idxs[c] = (c & 1) ? pi2[p] : pi1[p];
    }
    double cv[8];
#pragma unroll
    for (int c = 0; c < 8; ++c)
        cv[c] = (double)cb[(size_t)idxs[c] * VQD + lane];

    double bestv = -1.0e300; int besti = 0x7fffffff;
#pragma unroll
    for (int c = 0; c < 8; ++c) {
        double t = fd * cv[c];
        for (int m = 32; m >= 1; m >>= 1) t += __shfl_xor(t, m, 64);
        double sim = t * invnD[(size_t)f * NEMB + idxs[c]];
        int idx = idxs[c];
        if (sim > bestv || (sim == bestv && idx < besti)) { bestv = sim; besti = idx; }
    }
    if (lane == 0) out[task] = besti;
}

// ---------------- launch ----------------
extern "C" void kernel_launch(void* const* d_in, const int* in_sizes, int n_in,
                              void* d_out, int out_size, void* d_ws, size_t ws_size,
                              hipStream_t stream)
{
    const float* x     = (const float*)d_in[0];
    const float* projA = (const float*)d_in[1];
    const float* projP = (const float*)d_in[2];
    const float* cbA   = (const float*)d_in[3];
    const float* cbP   = (const float*)d_in[4];

    char* ws = (char*)d_ws;
    unsigned short* ftH   = (unsigned short*)(ws + OFF_FTH);
    unsigned short* ftL   = (unsigned short*)(ws + OFF_FTL);
    unsigned short* cbHp  = (unsigned short*)(ws + OFF_CBH);
    unsigned short* cbLp  = (unsigned short*)(ws + OFF_CBL);
    double*         featD = (double*)(ws + OFF_FD);
    double*         invnD = (double*)(ws + OFF_INV);
    int*            pi1   = (int*)(ws + OFF_PI1);
    int*            pi2   = (int*)(ws + OFF_PI2);

    dft_proj_kernel<<<ROWS / 8, 128, 0, stream>>>(x, projA, projP, ftH, ftL, featD);
    cb_prep_kernel<<<dim3(NEMB / 64, 2), 256, 0, stream>>>(cbA, cbP, cbHp, cbLp, invnD);
    argmax_kernel<<<dim3(ROWS / 128, 2, 4), 256, 0, stream>>>(ftH, ftL, cbHp, cbLp, pi1, pi2);
    rescore_kernel<<<(2 * ROWS) / 4, 256, 0, stream>>>(featD, invnD, cbA, cbP, pi1, pi2, (int*)d_out);
}